// Round 8
// baseline (626.677 us; speedup 1.0000x reference)
//
#include <hip/hip_runtime.h>
#include <math.h>

#define BB 16
#define TT 512
#define IND 128
#define HH 256
#define DD 8
#define EPSF 1e-5f
#define EE 8          // steps per chunk
#define NCH (TT / EE) // 64 chunks

typedef _Float16 h2_t __attribute__((ext_vector_type(2)));

// tanh(x) = 1 - 2/(e^{2x}+1); exp overflow/underflow saturates to +-1 correctly.
__device__ __forceinline__ float fast_tanh(float x) {
    const float e = __expf(2.f * x);
    return fmaf(-2.f, __frcp_rn(e + 1.f), 1.f);
}

// Workgroup barrier that waits only on LDS ops (lgkmcnt), NOT on outstanding global
// loads/stores — keeps chunked global traffic in flight across steps.
__device__ __forceinline__ void lds_barrier() {
    asm volatile("s_waitcnt lgkmcnt(0)\n\ts_barrier" ::: "memory");
}

// ---------------- K1: x_proj[b,t,j] = y[b,t,:]·W_ih[j,:] + b_ih[j] + b_hh[j] ----------------
__global__ __launch_bounds__(512, 4) void xproj_kernel(
    const float* __restrict__ y, const float* __restrict__ W_ih,
    const float* __restrict__ b_ih, const float* __restrict__ b_hh,
    float* __restrict__ xp)
{
    __shared__ __align__(16) float ylds[16 * IND];  // 8 KB = 512 float4
    const int tid = threadIdx.x;
    const int j = tid >> 1;
    const int k4 = (tid & 1) * 4;

    float4 w[16];
    const float* wr = W_ih + (size_t)j * IND + k4;
#pragma unroll
    for (int i = 0; i < 16; ++i) w[i] = *(const float4*)(wr + i * 8);
    const float bias = b_ih[j] + b_hh[j];

    const int row0 = blockIdx.x * 16;
    ((float4*)ylds)[tid] = ((const float4*)(y + (size_t)row0 * IND))[tid];
    __syncthreads();

    for (int r = 0; r < 16; ++r) {
        const float* yr = ylds + r * IND;
        float a0 = 0.f, a1 = 0.f, a2 = 0.f, a3 = 0.f;
#pragma unroll
        for (int i = 0; i < 16; ++i) {
            const float4 hv = *(const float4*)(yr + i * 8 + k4);
            a0 = fmaf(hv.x, w[i].x, a0);
            a1 = fmaf(hv.y, w[i].y, a1);
            a2 = fmaf(hv.z, w[i].z, a2);
            a3 = fmaf(hv.w, w[i].w, a3);
        }
        float acc = (a0 + a1) + (a2 + a3);
        acc += __shfl_xor(acc, 1);
        if ((tid & 1) == 0) xp[(size_t)(row0 + r) * HH + j] = acc + bias;
    }
}

// ---------------- K2: RNN scan (blocks 0..15) + prec zero-fill (blocks 16..) ----------------
// One block of 512 per batch. Thread (jb = tid>>3, k = tid&7) computes 4 contiguous outputs
// over a 32-wide k-slice (64 h2 weight VGPRs, 4 ds_read_b128 of h per step).
// NO global ops in the per-step chain: x is chunk-prefetched into registers (double-
// buffered, 8 steps of slack) and enc rows are staged in a double-buffered LDS tile,
// drained once per chunk with one coalesced float4 store per thread.
__global__ __launch_bounds__(512, 2) void scan_fill_kernel(
    const float* __restrict__ xp, const float* __restrict__ W_hh,
    float* __restrict__ enc, float* __restrict__ prec)
{
    if (blockIdx.x >= BB) {
        const size_t n4 = (size_t)BB * DD * TT * TT / 4;
        const float4 z = make_float4(0.f, 0.f, 0.f, 0.f);
        float4* p4 = (float4*)prec;
        size_t idx = (size_t)(blockIdx.x - BB) * blockDim.x + threadIdx.x;
        const size_t stride = (size_t)(gridDim.x - BB) * blockDim.x;
        for (; idx < n4; idx += stride) p4[idx] = z;
        return;
    }

    const int b = blockIdx.x;
    const int tid = threadIdx.x;
    const int jb = tid >> 3;   // 0..63
    const int k = tid & 7;     // 0..7
    const int j0 = jb * 4;     // first of 4 contiguous outputs

    __shared__ __align__(16) char hbufA[8 * 80];
    __shared__ __align__(16) char hbufB[8 * 80];
    __shared__ __align__(16) float encstage[2][EE * HH];  // 2 x 8 KB

    // weights: w[r][i] = W_hh[j0+r][k*32 + 2i .. +1], 16 h2 per output, 64 VGPRs total
    h2_t w[4][16];
#pragma unroll
    for (int r = 0; r < 4; ++r) {
        const float* wr = W_hh + (size_t)(j0 + r) * HH + (size_t)k * 32;
#pragma unroll
        for (int i = 0; i < 16; ++i) {
            h2_t v;
            v.x = (_Float16)wr[2 * i];
            v.y = (_Float16)wr[2 * i + 1];
            w[r][i] = v;
        }
    }

    if (tid < 160) ((float*)hbufA)[tid] = 0.f;  // zero data+pads (pads never read)
    __syncthreads();

    const float* xpb = xp + (size_t)b * TT * HH;
    float* encb = enc + (size_t)b * TT * HH;

    // preload chunk 0 of x
    float4 xcur[EE], xnext[EE];
#pragma unroll
    for (int e = 0; e < EE; ++e) xcur[e] = *(const float4*)(xpb + (size_t)e * HH + j0);

    const char* hrd = hbufA;
    char* hwr = hbufB;
    for (int c = 0; c < NCH; ++c) {
        const int tbase = c * EE;
        const int nbase = (c < NCH - 1) ? tbase + EE : tbase;
#pragma unroll
        for (int e = 0; e < EE; ++e)
            xnext[e] = *(const float4*)(xpb + (size_t)(nbase + e) * HH + j0);

        float* stg = encstage[c & 1];
#pragma unroll
        for (int e = 0; e < EE; ++e) {
            // read this thread's 32-half slice of h: 4 x b128, conflict-free
            union { float4 f4; h2_t h[4]; } u0, u1, u2, u3;
            const float4* hp = (const float4*)(hrd + k * 80);
            u0.f4 = hp[0]; u1.f4 = hp[1]; u2.f4 = hp[2]; u3.f4 = hp[3];

            float a0 = 0.f, a1 = 0.f, a2 = 0.f, a3 = 0.f;
#pragma unroll
            for (int q = 0; q < 4; ++q) {
                a0 = __builtin_amdgcn_fdot2(u0.h[q], w[0][q], a0, false);
                a1 = __builtin_amdgcn_fdot2(u0.h[q], w[1][q], a1, false);
                a2 = __builtin_amdgcn_fdot2(u0.h[q], w[2][q], a2, false);
                a3 = __builtin_amdgcn_fdot2(u0.h[q], w[3][q], a3, false);
                a0 = __builtin_amdgcn_fdot2(u1.h[q], w[0][4 + q], a0, false);
                a1 = __builtin_amdgcn_fdot2(u1.h[q], w[1][4 + q], a1, false);
                a2 = __builtin_amdgcn_fdot2(u1.h[q], w[2][4 + q], a2, false);
                a3 = __builtin_amdgcn_fdot2(u1.h[q], w[3][4 + q], a3, false);
                a0 = __builtin_amdgcn_fdot2(u2.h[q], w[0][8 + q], a0, false);
                a1 = __builtin_amdgcn_fdot2(u2.h[q], w[1][8 + q], a1, false);
                a2 = __builtin_amdgcn_fdot2(u2.h[q], w[2][8 + q], a2, false);
                a3 = __builtin_amdgcn_fdot2(u2.h[q], w[3][8 + q], a3, false);
                a0 = __builtin_amdgcn_fdot2(u3.h[q], w[0][12 + q], a0, false);
                a1 = __builtin_amdgcn_fdot2(u3.h[q], w[1][12 + q], a1, false);
                a2 = __builtin_amdgcn_fdot2(u3.h[q], w[2][12 + q], a2, false);
                a3 = __builtin_amdgcn_fdot2(u3.h[q], w[3][12 + q], a3, false);
            }
            // k-reduce (lane bits 0..2 = k)
            a0 += __shfl_xor(a0, 1); a1 += __shfl_xor(a1, 1);
            a2 += __shfl_xor(a2, 1); a3 += __shfl_xor(a3, 1);
            a0 += __shfl_xor(a0, 2); a1 += __shfl_xor(a1, 2);
            a2 += __shfl_xor(a2, 2); a3 += __shfl_xor(a3, 2);
            a0 += __shfl_xor(a0, 4); a1 += __shfl_xor(a1, 4);
            a2 += __shfl_xor(a2, 4); a3 += __shfl_xor(a3, 4);

            const float h0 = fast_tanh(xcur[e].x + a0);
            const float h1 = fast_tanh(xcur[e].y + a1);
            const float h2 = fast_tanh(xcur[e].z + a2);
            const float h3 = fast_tanh(xcur[e].w + a3);

            if (k == 0) {
                *(float4*)(stg + e * HH + j0) = make_float4(h0, h1, h2, h3);  // LDS stage
                h2_t p0, p1;
                p0.x = (_Float16)h0; p0.y = (_Float16)h1;
                p1.x = (_Float16)h2; p1.y = (_Float16)h3;
                h2_t* dst = (h2_t*)(hwr + (jb >> 3) * 80 + (jb & 7) * 8);
                dst[0] = p0; dst[1] = p1;
            }
            lds_barrier();  // lgkmcnt only — chunked global traffic stays in flight
            const char* tmp = hrd; hrd = hwr; hwr = (char*)tmp;
        }

        // drain staged enc rows: 8 rows x 256 floats = 512 float4, one per thread
        {
            const float4 v = ((const float4*)stg)[tid];
            ((float4*)(encb + (size_t)tbase * HH))[tid] = v;
        }
#pragma unroll
        for (int e = 0; e < EE; ++e) xcur[e] = xnext[e];
    }
}

// ---------------- K3: heads + tridiagonal fill ----------------
__global__ __launch_bounds__(256) void head_kernel(
    const float* __restrict__ enc,
    const float* __restrict__ W_mean, const float* __restrict__ b_mean,
    const float* __restrict__ W_bd, const float* __restrict__ b_bd,
    float* __restrict__ mean_out, float* __restrict__ prec)
{
    const int b = blockIdx.x >> 6;
    const int t0 = (blockIdx.x & 63) * 8;
    __shared__ __align__(16) float erow[9][HH];  // rows t0-1 .. t0+7
    __shared__ float vals[8][32];

    const int tid = threadIdx.x;
    {
        // row t0-1 (for t0==0,b==0 this reads the tail of xp — harmless, discarded)
        const float4* src = (const float4*)(enc + ((size_t)b * TT + t0) * HH - HH);
        float4* dst = (float4*)erow;
        for (int i = tid; i < 9 * (HH / 4); i += 256) dst[i] = src[i];
    }

    const int g = tid >> 3, m = tid & 7;
    const float* wrow;
    float bias;
    if (g < 8)       { wrow = W_mean + (size_t)g * HH;      bias = b_mean[g]; }
    else if (g < 24) { wrow = W_bd + (size_t)(g - 8) * HH;  bias = b_bd[g - 8]; }
    else             { wrow = W_bd + (size_t)(g - 16) * HH; bias = b_bd[g - 16]; }

    float4 wv[8];
#pragma unroll
    for (int i = 0; i < 8; ++i) wv[i] = ((const float4*)wrow)[m * 8 + i];

    __syncthreads();

    for (int r = 0; r < 8; ++r) {
        const float* src = (g >= 24) ? erow[r] : erow[r + 1];
        float acc = 0.f;
#pragma unroll
        for (int i = 0; i < 8; ++i) {
            const float4 hv = ((const float4*)src)[m * 8 + i];
            acc += wv[i].x * hv.x + wv[i].y * hv.y + wv[i].z * hv.z + wv[i].w * hv.w;
        }
        acc += __shfl_xor(acc, 1);
        acc += __shfl_xor(acc, 2);
        acc += __shfl_xor(acc, 4);
        if (m == 0) vals[r][g] = acc + bias;
    }
    __syncthreads();

    const int r = tid >> 5, s = tid & 31;
    const int t = t0 + r;
    if (s < DD) {
        mean_out[((size_t)b * TT + t) * DD + s] = vals[r][s];
    } else if (s < 2 * DD) {
        const int d = s - DD;
        const float diag = vals[r][8 + d];
        const float off  = vals[r][16 + d];
        const float offp = (t > 0) ? vals[r][24 + d] : 0.f;
        const size_t rowbase = (((size_t)b * DD + d) * TT + t) * TT;
        prec[rowbase + t] = diag * diag + offp * offp + EPSF;
        if (t < TT - 1) {
            const float sv = diag * off;
            prec[rowbase + t + 1] = sv;                                 // (t, t+1)
            prec[(((size_t)b * DD + d) * TT + (t + 1)) * TT + t] = sv;  // (t+1, t)
        }
    }
}

extern "C" void kernel_launch(void* const* d_in, const int* in_sizes, int n_in,
                              void* d_out, int out_size, void* d_ws, size_t ws_size,
                              hipStream_t stream) {
    const float* y      = (const float*)d_in[0];
    const float* W_ih   = (const float*)d_in[1];
    const float* W_hh   = (const float*)d_in[2];
    const float* b_ih   = (const float*)d_in[3];
    const float* b_hh   = (const float*)d_in[4];
    const float* W_mean = (const float*)d_in[5];
    const float* b_mean = (const float*)d_in[6];
    const float* W_bd   = (const float*)d_in[7];
    const float* b_bd   = (const float*)d_in[8];

    float* out  = (float*)d_out;
    float* mean = out;                              // B*T*D floats
    float* prec = out + (size_t)BB * TT * DD;       // B*D*T*T floats

    float* xp  = (float*)d_ws;                      // B*T*H floats = 8 MB
    float* enc = xp + (size_t)BB * TT * HH;         // B*T*H floats = 8 MB

    xproj_kernel<<<512, 512, 0, stream>>>(y, W_ih, b_ih, b_hh, xp);
    scan_fill_kernel<<<256, 512, 0, stream>>>(xp, W_hh, enc, prec);
    head_kernel<<<1024, 256, 0, stream>>>(enc, W_mean, b_mean, W_bd, b_bd, mean, prec);
}

// Round 9
// 538.826 us; speedup vs baseline: 1.1630x; 1.1630x over previous
//
#include <hip/hip_runtime.h>
#include <math.h>

#define BB 16
#define TT 512
#define IND 128
#define HH 256
#define DD 8
#define EPSF 1e-5f

typedef _Float16 h2_t __attribute__((ext_vector_type(2)));

__device__ __forceinline__ float fast_tanh(float x) {
    x = fminf(fmaxf(x, -15.f), 15.f);
    const float e = __expf(2.f * x);
    return __fdividef(e - 1.f, e + 1.f);
}

// ---------------- K1: x_proj + prec zero-fill ----------------
// 512 blocks x 512 threads: j = tid>>1, k = tid&1 (64-wide half-dot). All 16 y-rows staged
// to LDS once, 16 row-dots from broadcast LDS reads. Then each block grid-strides part of
// the 128 MB prec zero-fill (overlaps across the full chip; scan no longer carries it).
__global__ __launch_bounds__(512, 4) void xproj_fill_kernel(
    const float* __restrict__ y, const float* __restrict__ W_ih,
    const float* __restrict__ b_ih, const float* __restrict__ b_hh,
    float* __restrict__ xp, float* __restrict__ prec)
{
    __shared__ __align__(16) float ylds[16 * IND];  // 8 KB = 512 float4
    const int tid = threadIdx.x;
    const int j = tid >> 1;
    const int k4 = (tid & 1) * 4;

    float4 w[16];
    const float* wr = W_ih + (size_t)j * IND + k4;
#pragma unroll
    for (int i = 0; i < 16; ++i) w[i] = *(const float4*)(wr + i * 8);
    const float bias = b_ih[j] + b_hh[j];

    const int row0 = blockIdx.x * 16;
    ((float4*)ylds)[tid] = ((const float4*)(y + (size_t)row0 * IND))[tid];
    __syncthreads();

    for (int r = 0; r < 16; ++r) {
        const float* yr = ylds + r * IND;
        float a0 = 0.f, a1 = 0.f, a2 = 0.f, a3 = 0.f;
#pragma unroll
        for (int i = 0; i < 16; ++i) {
            const float4 hv = *(const float4*)(yr + i * 8 + k4);
            a0 = fmaf(hv.x, w[i].x, a0);
            a1 = fmaf(hv.y, w[i].y, a1);
            a2 = fmaf(hv.z, w[i].z, a2);
            a3 = fmaf(hv.w, w[i].w, a3);
        }
        float acc = (a0 + a1) + (a2 + a3);
        acc += __shfl_xor(acc, 1);
        if ((tid & 1) == 0) xp[(size_t)(row0 + r) * HH + j] = acc + bias;
    }

    // grid-stride zero-fill of prec (128 MB) across all 512 blocks
    {
        const size_t n4 = (size_t)BB * DD * TT * TT / 4;  // 8388608 float4
        const float4 z = make_float4(0.f, 0.f, 0.f, 0.f);
        float4* p4 = (float4*)prec;
        size_t idx = (size_t)blockIdx.x * blockDim.x + tid;
        const size_t stride = (size_t)gridDim.x * blockDim.x;
        for (; idx < n4; idx += stride) p4[idx] = z;
    }
}

// ---------------- K2: RNN scan — measured-best structure (round-3 proposal, 372 us) -----
// 16 blocks x 1024 threads: j = tid>>2 (output), k = tid&3 (64-wide dot slice, f16 dot2).
// h kept in LDS as f16, 4 slices of 144 B (128 B data + 16 B pad). 32 fdot2 per thread,
// 2 shfl_xor k-reduce, one __syncthreads per step. 16 waves/CU hide the chain latency.
__global__ __launch_bounds__(1024, 4) void scan_kernel(
    const float* __restrict__ xp, const float* __restrict__ W_hh,
    float* __restrict__ enc)
{
    const int b = blockIdx.x;
    const int tid = threadIdx.x;
    const int j = tid >> 2;
    const int k = tid & 3;

    // each k-slice: 64 halves = 128 B, padded to 144 B
    __shared__ __align__(16) char hbufA[4 * 144];
    __shared__ __align__(16) char hbufB[4 * 144];

    // weights: W_hh[j, k*64 + m], m = 0..63, packed as 32 f16-pairs
    h2_t w[32];
    {
        const float* wr = W_hh + (size_t)j * HH + (size_t)k * 64;
#pragma unroll
        for (int i = 0; i < 32; ++i) {
            h2_t v;
            v.x = (_Float16)wr[2 * i];
            v.y = (_Float16)wr[2 * i + 1];
            w[i] = v;
        }
    }
#pragma unroll
    for (int i = 0; i < 32; ++i) {
        int tmp = __builtin_bit_cast(int, w[i]);
        asm volatile("" : "+v"(tmp));
        w[i] = __builtin_bit_cast(h2_t, tmp);
    }

    // zero-init hbufA (pads don't matter: never read)
    if (tid < 128) {
        const int m = 2 * tid;
        h2_t z; z.x = (_Float16)0.f; z.y = (_Float16)0.f;
        *(h2_t*)(hbufA + (m >> 6) * 144 + (m & 63) * 2) = z;
    }
    __syncthreads();

    const float* xpb = xp + (size_t)b * TT * HH;
    float* encb = enc + (size_t)b * TT * HH;

    const char* hrd = hbufA;
    char* hwr = hbufB;
    float xc = xpb[j];  // t = 0
    for (int t = 0; t < TT; ++t) {
        const int tn = (t < TT - 1) ? t + 1 : t;
        const float xn = xpb[(size_t)tn * HH + j];  // prefetch next x

        float a0 = 0.f, a1 = 0.f, a2 = 0.f, a3 = 0.f;
        const float4* hp = (const float4*)(hrd + k * 144);
#pragma unroll
        for (int i = 0; i < 8; ++i) {
            union { float4 f4; h2_t h[4]; } u;
            u.f4 = hp[i];
            a0 = __builtin_amdgcn_fdot2(u.h[0], w[4 * i + 0], a0, false);
            a1 = __builtin_amdgcn_fdot2(u.h[1], w[4 * i + 1], a1, false);
            a2 = __builtin_amdgcn_fdot2(u.h[2], w[4 * i + 2], a2, false);
            a3 = __builtin_amdgcn_fdot2(u.h[3], w[4 * i + 3], a3, false);
        }
        float p = (a0 + a1) + (a2 + a3);
        p += __shfl_xor(p, 1);
        p += __shfl_xor(p, 2);
        const float hn = fast_tanh(xc + p);
        const float hnp = __shfl_xor(hn, 4);  // partner j^1 (same k)
        if (k == 0) {
            encb[(size_t)t * HH + j] = hn;
            if ((j & 1) == 0) {
                h2_t hv; hv.x = (_Float16)hn; hv.y = (_Float16)hnp;
                *(h2_t*)(hwr + (j >> 6) * 144 + (j & 63) * 2) = hv;
            }
        }
        __syncthreads();
        const char* tmp = hrd; hrd = hwr; hwr = (char*)tmp;
        xc = xn;
    }
}

// ---------------- K3: heads + tridiagonal fill ----------------
// 1024 blocks: each handles one b and 8 consecutive t. 9 enc rows staged in LDS once;
// per t, 32 groups of 8 lanes compute the 24 distinct dots; one barrier before writes.
__global__ __launch_bounds__(256) void head_kernel(
    const float* __restrict__ enc,
    const float* __restrict__ W_mean, const float* __restrict__ b_mean,
    const float* __restrict__ W_bd, const float* __restrict__ b_bd,
    float* __restrict__ mean_out, float* __restrict__ prec)
{
    const int b = blockIdx.x >> 6;
    const int t0 = (blockIdx.x & 63) * 8;
    __shared__ __align__(16) float erow[9][HH];  // rows t0-1 .. t0+7
    __shared__ float vals[8][32];

    const int tid = threadIdx.x;
    {
        // row t0-1 (for t0==0,b==0 this reads the tail of xp — harmless, discarded)
        const float4* src = (const float4*)(enc + ((size_t)b * TT + t0) * HH - HH);
        float4* dst = (float4*)erow;
        for (int i = tid; i < 9 * (HH / 4); i += 256) dst[i] = src[i];
    }

    const int g = tid >> 3, m = tid & 7;
    const float* wrow;
    float bias;
    if (g < 8)       { wrow = W_mean + (size_t)g * HH;      bias = b_mean[g]; }
    else if (g < 24) { wrow = W_bd + (size_t)(g - 8) * HH;  bias = b_bd[g - 8]; }
    else             { wrow = W_bd + (size_t)(g - 16) * HH; bias = b_bd[g - 16]; }

    float4 wv[8];
#pragma unroll
    for (int i = 0; i < 8; ++i) wv[i] = ((const float4*)wrow)[m * 8 + i];

    __syncthreads();

    for (int r = 0; r < 8; ++r) {
        const float* src = (g >= 24) ? erow[r] : erow[r + 1];
        float acc = 0.f;
#pragma unroll
        for (int i = 0; i < 8; ++i) {
            const float4 hv = ((const float4*)src)[m * 8 + i];
            acc += wv[i].x * hv.x + wv[i].y * hv.y + wv[i].z * hv.z + wv[i].w * hv.w;
        }
        acc += __shfl_xor(acc, 1);
        acc += __shfl_xor(acc, 2);
        acc += __shfl_xor(acc, 4);
        if (m == 0) vals[r][g] = acc + bias;
    }
    __syncthreads();

    const int r = tid >> 5, s = tid & 31;
    const int t = t0 + r;
    if (s < DD) {
        mean_out[((size_t)b * TT + t) * DD + s] = vals[r][s];
    } else if (s < 2 * DD) {
        const int d = s - DD;
        const float diag = vals[r][8 + d];
        const float off  = vals[r][16 + d];
        const float offp = (t > 0) ? vals[r][24 + d] : 0.f;
        const size_t rowbase = (((size_t)b * DD + d) * TT + t) * TT;
        prec[rowbase + t] = diag * diag + offp * offp + EPSF;
        if (t < TT - 1) {
            const float sv = diag * off;
            prec[rowbase + t + 1] = sv;                                 // (t, t+1)
            prec[(((size_t)b * DD + d) * TT + (t + 1)) * TT + t] = sv;  // (t+1, t)
        }
    }
}

extern "C" void kernel_launch(void* const* d_in, const int* in_sizes, int n_in,
                              void* d_out, int out_size, void* d_ws, size_t ws_size,
                              hipStream_t stream) {
    const float* y      = (const float*)d_in[0];
    const float* W_ih   = (const float*)d_in[1];
    const float* W_hh   = (const float*)d_in[2];
    const float* b_ih   = (const float*)d_in[3];
    const float* b_hh   = (const float*)d_in[4];
    const float* W_mean = (const float*)d_in[5];
    const float* b_mean = (const float*)d_in[6];
    const float* W_bd   = (const float*)d_in[7];
    const float* b_bd   = (const float*)d_in[8];

    float* out  = (float*)d_out;
    float* mean = out;                              // B*T*D floats
    float* prec = out + (size_t)BB * TT * DD;       // B*D*T*T floats

    float* xp  = (float*)d_ws;                      // B*T*H floats = 8 MB
    float* enc = xp + (size_t)BB * TT * HH;         // B*T*H floats = 8 MB

    xproj_fill_kernel<<<512, 512, 0, stream>>>(y, W_ih, b_ih, b_hh, xp, prec);
    scan_kernel<<<BB, 1024, 0, stream>>>(xp, W_hh, enc);
    head_kernel<<<1024, 256, 0, stream>>>(enc, W_mean, b_mean, W_bd, b_bd, mean, prec);
}